// Round 1
// baseline (604.726 us; speedup 1.0000x reference)
//
#include <hip/hip_runtime.h>
#include <math.h>

#define D 128

// ---------------- CSR build ----------------

__global__ void k_count(const int* __restrict__ src, const int* __restrict__ dst,
                        int* __restrict__ cs, int* __restrict__ cd, int E) {
  int i = blockIdx.x * blockDim.x + threadIdx.x;
  if (i < E) {
    atomicAdd(&cs[src[i]], 1);
    atomicAdd(&cd[dst[i]], 1);
  }
}

__global__ void k_norms(const int* __restrict__ cs, const int* __restrict__ cd,
                        float* __restrict__ ns, float* __restrict__ nd, int n) {
  int i = blockIdx.x * blockDim.x + threadIdx.x;
  if (i < n) {
    int a = cs[i]; if (a < 1) a = 1;
    int b = cd[i]; if (b < 1) b = 1;
    ns[i] = 1.0f / sqrtf((float)a);
    nd[i] = 1.0f / sqrtf((float)b);
  }
}

__global__ __launch_bounds__(256) void k_scan_partial(const int* __restrict__ cd,
                                                      int* __restrict__ csum, int n) {
  __shared__ int sd[256];
  const int b = blockIdx.x, t = threadIdx.x;
  const int base = b * 1024 + t * 4;
  int s = 0;
#pragma unroll
  for (int i = 0; i < 4; ++i) { int idx = base + i; if (idx < n) s += cd[idx]; }
  sd[t] = s; __syncthreads();
  for (int off = 128; off > 0; off >>= 1) {
    if (t < off) sd[t] += sd[t + off];
    __syncthreads();
  }
  if (t == 0) csum[b] = sd[0];
}

__global__ void k_scan_serial(int* __restrict__ csum, int nch,
                              int* __restrict__ rofs, int n) {
  if (blockIdx.x == 0 && threadIdx.x == 0) {
    int run = 0;
    for (int b = 0; b < nch; ++b) { int v = csum[b]; csum[b] = run; run += v; }
    rofs[n] = run;
  }
}

__global__ __launch_bounds__(256) void k_scan_final(const int* __restrict__ cd,
                                                    const int* __restrict__ csum,
                                                    int* __restrict__ rofs, int n) {
  __shared__ int sd[256];
  const int b = blockIdx.x, t = threadIdx.x;
  const int base = b * 1024 + t * 4;
  int v[4]; int s = 0;
#pragma unroll
  for (int i = 0; i < 4; ++i) { v[i] = (base + i < n) ? cd[base + i] : 0; s += v[i]; }
  sd[t] = s; __syncthreads();
  for (int off = 1; off < 256; off <<= 1) {
    int x = (t >= off) ? sd[t - off] : 0;
    __syncthreads();
    sd[t] += x;
    __syncthreads();
  }
  int o = sd[t] - s + csum[b];
#pragma unroll
  for (int i = 0; i < 4; ++i) {
    if (base + i < n) { rofs[base + i] = o; o += v[i]; }
  }
}

__global__ void k_fill(const int* __restrict__ src, const int* __restrict__ dst,
                       const int* __restrict__ rofs, int* __restrict__ cursor,
                       int* __restrict__ csr, int E) {
  int i = blockIdx.x * blockDim.x + threadIdx.x;
  if (i < E) {
    int d = dst[i];
    int pos = atomicAdd(&cursor[d], 1);
    csr[rofs[d] + pos] = src[i];
  }
}

// ---------------- GEMM: out[r,:] = (H[r,:]*ns[r]) @ W,  W is [D][D] ----------------

__global__ __launch_bounds__(256) void k_gemm(const float* __restrict__ H,
                                              const float* __restrict__ W,
                                              const float* __restrict__ ns,
                                              float* __restrict__ out, int M) {
  __shared__ float a_s[64][132];  // +4 pad: 2-way bank aliasing only (free)
  const int t = threadIdx.x;
  const int r0 = blockIdx.x * 64;
  {
    const int rr = t >> 5;   // 0..7
    const int cc = t & 31;   // float4 chunk within row
#pragma unroll
    for (int it = 0; it < 8; ++it) {
      const int r = rr + it * 8;
      const int row = r0 + r;
      float4 v = make_float4(0.f, 0.f, 0.f, 0.f);
      if (row < M) {
        v = *reinterpret_cast<const float4*>(H + (size_t)row * D + cc * 4);
        const float s = ns[row];
        v.x *= s; v.y *= s; v.z *= s; v.w *= s;
      }
      *reinterpret_cast<float4*>(&a_s[r][cc * 4]) = v;
    }
  }
  __syncthreads();
  const int tx = t & 15;   // 16 col-groups of 8
  const int ty = t >> 4;   // 16 row-groups of 4
  float acc[4][8];
#pragma unroll
  for (int i = 0; i < 4; ++i)
#pragma unroll
    for (int j = 0; j < 8; ++j) acc[i][j] = 0.f;

  const float* wp = W + tx * 8;
#pragma unroll 8
  for (int k = 0; k < D; ++k) {
    const float4 b0 = *reinterpret_cast<const float4*>(wp + (size_t)k * D);
    const float4 b1 = *reinterpret_cast<const float4*>(wp + (size_t)k * D + 4);
    float a[4];
#pragma unroll
    for (int i = 0; i < 4; ++i) a[i] = a_s[ty * 4 + i][k];
#pragma unroll
    for (int i = 0; i < 4; ++i) {
      acc[i][0] += a[i] * b0.x;
      acc[i][1] += a[i] * b0.y;
      acc[i][2] += a[i] * b0.z;
      acc[i][3] += a[i] * b0.w;
      acc[i][4] += a[i] * b1.x;
      acc[i][5] += a[i] * b1.y;
      acc[i][6] += a[i] * b1.z;
      acc[i][7] += a[i] * b1.w;
    }
  }
  const int c0 = tx * 8;
#pragma unroll
  for (int i = 0; i < 4; ++i) {
    const int row = r0 + ty * 4 + i;
    if (row < M) {
      float4 v0 = make_float4(acc[i][0], acc[i][1], acc[i][2], acc[i][3]);
      float4 v1 = make_float4(acc[i][4], acc[i][5], acc[i][6], acc[i][7]);
      *reinterpret_cast<float4*>(out + (size_t)row * D + c0) = v0;
      *reinterpret_cast<float4*>(out + (size_t)row * D + c0 + 4) = v1;
    }
  }
}

// ---------------- SpMM (gather over CSR) + fused norm/bias/BN/ReLU ----------------

__global__ __launch_bounds__(128) void k_spmm(const float* __restrict__ hs,
                                              const int* __restrict__ csr,
                                              const int* __restrict__ rofs,
                                              const float* __restrict__ nd,
                                              const float* __restrict__ bias,
                                              const float* __restrict__ g,
                                              const float* __restrict__ be,
                                              const float* __restrict__ mu,
                                              const float* __restrict__ vr,
                                              float* __restrict__ out, int bn_relu) {
  const int d = blockIdx.x;
  const int col = threadIdx.x;
  const int beg = rofs[d];
  const int end = rofs[d + 1];
  float acc = 0.f;
  int e = beg;
  for (; e + 4 <= end; e += 4) {
    const int s0 = csr[e], s1 = csr[e + 1], s2 = csr[e + 2], s3 = csr[e + 3];
    const float v0 = hs[(size_t)s0 * D + col];
    const float v1 = hs[(size_t)s1 * D + col];
    const float v2 = hs[(size_t)s2 * D + col];
    const float v3 = hs[(size_t)s3 * D + col];
    acc += (v0 + v1) + (v2 + v3);
  }
  for (; e < end; ++e) acc += hs[(size_t)csr[e] * D + col];
  float v = acc * nd[d] + bias[col];
  if (bn_relu) {
    v = (v - mu[col]) / sqrtf(vr[col] + 1e-5f) * g[col] + be[col];
    v = fmaxf(v, 0.f);
  }
  out[(size_t)d * D + col] = v;
}

// ---------------- launch ----------------

extern "C" void kernel_launch(void* const* d_in, const int* in_sizes, int n_in,
                              void* d_out, int out_size, void* d_ws, size_t ws_size,
                              hipStream_t stream) {
  const float* x = (const float*)d_in[0];
  const int* esrc = (const int*)d_in[1];
  const int* edst = (const int*)d_in[2];
  const float* Wm[3] = {(const float*)d_in[3], (const float*)d_in[5], (const float*)d_in[7]};
  const float* bs[3] = {(const float*)d_in[4], (const float*)d_in[6], (const float*)d_in[8]};
  const float* bng[2] = {(const float*)d_in[9], (const float*)d_in[13]};
  const float* bnb[2] = {(const float*)d_in[10], (const float*)d_in[14]};
  const float* bnm[2] = {(const float*)d_in[11], (const float*)d_in[15]};
  const float* bnv[2] = {(const float*)d_in[12], (const float*)d_in[16]};
  const int N = in_sizes[0] / D;
  const int E = in_sizes[1];

  char* p = (char*)d_ws;
  auto carve = [&](size_t bytes) {
    char* r = p;
    p += (bytes + 255) & ~(size_t)255;
    return (void*)r;
  };
  float* hs = (float*)carve((size_t)N * D * 4);   // GEMM output / SpMM input
  float* ns = (float*)carve((size_t)N * 4);
  float* nd = (float*)carve((size_t)N * 4);
  int* cs = (int*)carve((size_t)N * 4);
  int* cd = (int*)carve((size_t)N * 4);
  int* rofs = (int*)carve((size_t)(N + 1) * 4);
  int* cursor = (int*)carve((size_t)N * 4);
  const int nch = (N + 1023) / 1024;
  int* csum = (int*)carve((size_t)nch * 4);
  int* csr = (int*)carve((size_t)E * 4);
  float* htmp = (float*)d_out;  // inter-layer h lives in d_out (fully rewritten each layer)

  hipMemsetAsync(cs, 0, (size_t)N * 4, stream);
  hipMemsetAsync(cd, 0, (size_t)N * 4, stream);
  hipMemsetAsync(cursor, 0, (size_t)N * 4, stream);

  k_count<<<(E + 255) / 256, 256, 0, stream>>>(esrc, edst, cs, cd, E);
  k_norms<<<(N + 255) / 256, 256, 0, stream>>>(cs, cd, ns, nd, N);
  k_scan_partial<<<nch, 256, 0, stream>>>(cd, csum, N);
  k_scan_serial<<<1, 1, 0, stream>>>(csum, nch, rofs, N);
  k_scan_final<<<nch, 256, 0, stream>>>(cd, csum, rofs, N);
  k_fill<<<(E + 255) / 256, 256, 0, stream>>>(esrc, edst, rofs, cursor, csr, E);

  const int gblocks = (N + 63) / 64;
  // layer 0
  k_gemm<<<gblocks, 256, 0, stream>>>(x, Wm[0], ns, hs, N);
  k_spmm<<<N, 128, 0, stream>>>(hs, csr, rofs, nd, bs[0], bng[0], bnb[0], bnm[0], bnv[0], htmp, 1);
  // layer 1
  k_gemm<<<gblocks, 256, 0, stream>>>(htmp, Wm[1], ns, hs, N);
  k_spmm<<<N, 128, 0, stream>>>(hs, csr, rofs, nd, bs[1], bng[1], bnb[1], bnm[1], bnv[1], htmp, 1);
  // layer 2
  k_gemm<<<gblocks, 256, 0, stream>>>(htmp, Wm[2], ns, hs, N);
  k_spmm<<<N, 128, 0, stream>>>(hs, csr, rofs, nd, bs[2], bng[0], bnb[0], bnm[0], bnv[0],
                                (float*)d_out, 0);
}

// Round 2
// 450.571 us; speedup vs baseline: 1.3421x; 1.3421x over previous
//
#include <hip/hip_runtime.h>
#include <hip/hip_fp16.h>
#include <math.h>

#define D 128

typedef _Float16 half8 __attribute__((ext_vector_type(8)));
typedef float f32x4 __attribute__((ext_vector_type(4)));

__device__ inline uint pack_f16x2(float a, float b) {
  __half2 h = __floats2half2_rn(a, b);
  return *reinterpret_cast<uint*>(&h);
}
__device__ inline float2 unpack_f16x2(uint p) {
  __half2 h = *reinterpret_cast<__half2*>(&p);
  return __half22float2(h);
}

// ---------------- CSR build ----------------

__global__ void k_count(const int* __restrict__ src, const int* __restrict__ dst,
                        int* __restrict__ cs, int* __restrict__ cd, int E) {
  int i = blockIdx.x * blockDim.x + threadIdx.x;
  if (i < E) {
    atomicAdd(&cs[src[i]], 1);
    atomicAdd(&cd[dst[i]], 1);
  }
}

__global__ void k_norms(const int* __restrict__ cs, const int* __restrict__ cd,
                        float* __restrict__ ns, float* __restrict__ nd, int n) {
  int i = blockIdx.x * blockDim.x + threadIdx.x;
  if (i < n) {
    int a = cs[i]; if (a < 1) a = 1;
    int b = cd[i]; if (b < 1) b = 1;
    ns[i] = 1.0f / sqrtf((float)a);
    nd[i] = 1.0f / sqrtf((float)b);
  }
}

__global__ __launch_bounds__(256) void k_scan_partial(const int* __restrict__ cd,
                                                      int* __restrict__ csum, int n) {
  __shared__ int sd[256];
  const int b = blockIdx.x, t = threadIdx.x;
  const int base = b * 1024 + t * 4;
  int s = 0;
#pragma unroll
  for (int i = 0; i < 4; ++i) { int idx = base + i; if (idx < n) s += cd[idx]; }
  sd[t] = s; __syncthreads();
  for (int off = 128; off > 0; off >>= 1) {
    if (t < off) sd[t] += sd[t + off];
    __syncthreads();
  }
  if (t == 0) csum[b] = sd[0];
}

__global__ void k_scan_serial(int* __restrict__ csum, int nch,
                              int* __restrict__ rofs, int n) {
  if (blockIdx.x == 0 && threadIdx.x == 0) {
    int run = 0;
    for (int b = 0; b < nch; ++b) { int v = csum[b]; csum[b] = run; run += v; }
    rofs[n] = run;
  }
}

__global__ __launch_bounds__(256) void k_scan_final(const int* __restrict__ cd,
                                                    const int* __restrict__ csum,
                                                    int* __restrict__ rofs,
                                                    int* __restrict__ cursor, int n) {
  __shared__ int sd[256];
  const int b = blockIdx.x, t = threadIdx.x;
  const int base = b * 1024 + t * 4;
  int v[4]; int s = 0;
#pragma unroll
  for (int i = 0; i < 4; ++i) { v[i] = (base + i < n) ? cd[base + i] : 0; s += v[i]; }
  sd[t] = s; __syncthreads();
  for (int off = 1; off < 256; off <<= 1) {
    int x = (t >= off) ? sd[t - off] : 0;
    __syncthreads();
    sd[t] += x;
    __syncthreads();
  }
  int o = sd[t] - s + csum[b];
#pragma unroll
  for (int i = 0; i < 4; ++i) {
    if (base + i < n) { rofs[base + i] = o; cursor[base + i] = o; o += v[i]; }
  }
}

__global__ void k_fill(const int* __restrict__ src, const int* __restrict__ dst,
                       int* __restrict__ cursor, int* __restrict__ csr, int E) {
  int i = blockIdx.x * blockDim.x + threadIdx.x;
  if (i < E) {
    int pos = atomicAdd(&cursor[dst[i]], 1);  // absolute position (cursor init = rofs)
    csr[pos] = src[i];
  }
}

// ---------------- prep: Wt[l][n][k] = f16(W_l[k][n]); CA/CB fold bias+BN ----------------

__global__ void k_prep(const float* __restrict__ W0, const float* __restrict__ W1,
                       const float* __restrict__ W2,
                       const float* __restrict__ b0, const float* __restrict__ b1,
                       const float* __restrict__ b2,
                       const float* __restrict__ g0, const float* __restrict__ be0,
                       const float* __restrict__ mu0, const float* __restrict__ vr0,
                       const float* __restrict__ g1, const float* __restrict__ be1,
                       const float* __restrict__ mu1, const float* __restrict__ vr1,
                       ushort* __restrict__ Wt, float* __restrict__ CA,
                       float* __restrict__ CB) {
  int b = blockIdx.x;
  if (b < 192) {
    int li = b * 256 + threadIdx.x;  // 0..49151
    int l = li >> 14;
    int i = li & 16383;
    int n = i >> 7, k = i & 127;
    const float* W = (l == 0) ? W0 : ((l == 1) ? W1 : W2);
    Wt[li] = __half_as_ushort(__float2half_rn(W[k * D + n]));
  } else if (threadIdx.x < D) {
    int c = threadIdx.x;
    float A0 = g0[c] * rsqrtf(vr0[c] + 1e-5f);
    CA[c] = A0;
    CB[c] = (b0[c] - mu0[c]) * A0 + be0[c];
    float A1 = g1[c] * rsqrtf(vr1[c] + 1e-5f);
    CA[D + c] = A1;
    CB[D + c] = (b1[c] - mu1[c]) * A1 + be1[c];
    CA[2 * D + c] = 1.f;
    CB[2 * D + c] = b2[c];
  }
}

// ---------------- x16 = f16(x * ns) ----------------

__global__ void k_x16(const float* __restrict__ x, const float* __restrict__ ns,
                      uint* __restrict__ x16, int N) {
  int i = blockIdx.x * blockDim.x + threadIdx.x;  // one float4 (4 cols) per thread
  if (i < N * 32) {
    int r = i >> 5;
    float4 v = reinterpret_cast<const float4*>(x)[i];
    float s = ns[r];
    uint2 u;
    u.x = pack_f16x2(v.x * s, v.y * s);
    u.y = pack_f16x2(v.z * s, v.w * s);
    reinterpret_cast<uint2*>(x16)[i] = u;
  }
}

// ---------------- MFMA GEMM: out[m][n] = f16( A16[m][:] @ W[:,n] ) ----------------
// A16 row-major halves (already *ns). Wt[n][k] f16. Computes D = Wt_tile · A^T_tile = C^T.
// A-op frag: lane holds Wt[n0+(l&15)][k0+8*(l>>4)+j]   (16B contiguous)
// B-op frag: lane holds A16[m0+(l&15)][k0+8*(l>>4)+j]  (16B contiguous)
// D frag:    m = m0+(l&15), n = n0+4*(l>>4)+j

__global__ __launch_bounds__(256) void k_gemm16(const ushort* __restrict__ A,
                                                const ushort* __restrict__ Wt,
                                                ushort* __restrict__ out, int M) {
  const int lane = threadIdx.x & 63;
  const int wv = threadIdx.x >> 6;
  const int m0 = (blockIdx.x * 4 + wv) * 32;
  if (m0 >= M) return;
  const int lr = lane & 15;
  const int kg = (lane >> 4) * 8;

  half8 hf[2][4];
  const half8 hz = {};
#pragma unroll
  for (int mt = 0; mt < 2; ++mt) {
    const int row = m0 + mt * 16 + lr;
    const bool ok = row < M;
#pragma unroll
    for (int kt = 0; kt < 4; ++kt)
      hf[mt][kt] = ok ? *reinterpret_cast<const half8*>(A + (size_t)row * D + kt * 32 + kg)
                      : hz;
  }

  f32x4 acc[8][2];
#pragma unroll
  for (int nt = 0; nt < 8; ++nt) {
    acc[nt][0] = (f32x4)(0.f);
    acc[nt][1] = (f32x4)(0.f);
  }

#pragma unroll
  for (int nt = 0; nt < 8; ++nt) {
    const ushort* wb = Wt + (size_t)(nt * 16 + lr) * D + kg;
#pragma unroll
    for (int kt = 0; kt < 4; ++kt) {
      half8 wf = *reinterpret_cast<const half8*>(wb + kt * 32);
      acc[nt][0] = __builtin_amdgcn_mfma_f32_16x16x32_f16(wf, hf[0][kt], acc[nt][0], 0, 0, 0);
      acc[nt][1] = __builtin_amdgcn_mfma_f32_16x16x32_f16(wf, hf[1][kt], acc[nt][1], 0, 0, 0);
    }
  }

  const int mo = lane & 15;
  const int no = (lane >> 4) * 4;
#pragma unroll
  for (int mt = 0; mt < 2; ++mt) {
    const int row = m0 + mt * 16 + mo;
    if (row < M) {
#pragma unroll
      for (int nt = 0; nt < 8; ++nt) {
        uint2 u;
        u.x = pack_f16x2(acc[nt][mt][0], acc[nt][mt][1]);
        u.y = pack_f16x2(acc[nt][mt][2], acc[nt][mt][3]);
        *reinterpret_cast<uint2*>(out + (size_t)row * D + nt * 16 + no) = u;
      }
    }
  }
}

// ---------------- SpMM: gather f16 rows, fused (nd, CA/CB, ReLU, *ns -> f16) ----------------
// One wave per dst row; lane covers cols {2*lane, 2*lane+1} (one uint = half2).

__global__ __launch_bounds__(256) void k_spmm16(const uint* __restrict__ hs,
                                                const int* __restrict__ csr,
                                                const int* __restrict__ rofs,
                                                const float* __restrict__ nd,
                                                const float* __restrict__ ns,
                                                const float* __restrict__ CA,
                                                const float* __restrict__ CB,
                                                float* __restrict__ outf,
                                                uint* __restrict__ hnext,
                                                int N, int last) {
  const int lane = threadIdx.x & 63;
  const int d = blockIdx.x * 4 + (threadIdx.x >> 6);
  if (d >= N) return;
  int e = rofs[d];
  const int end = rofs[d + 1];
  float ax = 0.f, ay = 0.f;
  for (; e + 4 <= end; e += 4) {
    const int s0 = csr[e], s1 = csr[e + 1], s2 = csr[e + 2], s3 = csr[e + 3];
    const float2 v0 = unpack_f16x2(hs[(size_t)s0 * 64 + lane]);
    const float2 v1 = unpack_f16x2(hs[(size_t)s1 * 64 + lane]);
    const float2 v2 = unpack_f16x2(hs[(size_t)s2 * 64 + lane]);
    const float2 v3 = unpack_f16x2(hs[(size_t)s3 * 64 + lane]);
    ax += (v0.x + v1.x) + (v2.x + v3.x);
    ay += (v0.y + v1.y) + (v2.y + v3.y);
  }
  for (; e < end; ++e) {
    const float2 v = unpack_f16x2(hs[(size_t)csr[e] * 64 + lane]);
    ax += v.x;
    ay += v.y;
  }
  const float ndv = nd[d];
  const float2 ca = *reinterpret_cast<const float2*>(CA + lane * 2);
  const float2 cb = *reinterpret_cast<const float2*>(CB + lane * 2);
  float v0 = ax * ndv * ca.x + cb.x;
  float v1 = ay * ndv * ca.y + cb.y;
  if (!last) {
    v0 = fmaxf(v0, 0.f);
    v1 = fmaxf(v1, 0.f);
    const float s = ns[d];
    hnext[(size_t)d * 64 + lane] = pack_f16x2(v0 * s, v1 * s);
  } else {
    float2 o;
    o.x = v0;
    o.y = v1;
    *reinterpret_cast<float2*>(outf + (size_t)d * D + lane * 2) = o;
  }
}

// ---------------- launch ----------------

extern "C" void kernel_launch(void* const* d_in, const int* in_sizes, int n_in,
                              void* d_out, int out_size, void* d_ws, size_t ws_size,
                              hipStream_t stream) {
  const float* x = (const float*)d_in[0];
  const int* esrc = (const int*)d_in[1];
  const int* edst = (const int*)d_in[2];
  const float* W0 = (const float*)d_in[3];
  const float* b0 = (const float*)d_in[4];
  const float* W1 = (const float*)d_in[5];
  const float* b1 = (const float*)d_in[6];
  const float* W2 = (const float*)d_in[7];
  const float* b2 = (const float*)d_in[8];
  const float* g0 = (const float*)d_in[9];
  const float* be0 = (const float*)d_in[10];
  const float* m0 = (const float*)d_in[11];
  const float* v0 = (const float*)d_in[12];
  const float* g1 = (const float*)d_in[13];
  const float* be1 = (const float*)d_in[14];
  const float* m1 = (const float*)d_in[15];
  const float* v1 = (const float*)d_in[16];
  const int N = in_sizes[0] / D;
  const int E = in_sizes[1];

  char* p = (char*)d_ws;
  auto carve = [&](size_t bytes) {
    char* r = p;
    p += (bytes + 255) & ~(size_t)255;
    return (void*)r;
  };
  uint* hs16 = (uint*)carve((size_t)N * 64 * 4);   // GEMM out / SpMM in (f16 packed)
  uint* bufA = (uint*)carve((size_t)N * 64 * 4);   // GEMM in (f16, *ns)
  ushort* Wt = (ushort*)carve((size_t)3 * D * D * 2);
  float* CA = (float*)carve((size_t)3 * D * 4);
  float* CB = (float*)carve((size_t)3 * D * 4);
  float* ns = (float*)carve((size_t)N * 4);
  float* nd = (float*)carve((size_t)N * 4);
  int* cs = (int*)carve((size_t)2 * N * 4);  // cs,cd contiguous -> one memset
  int* cd = cs + N;
  int* rofs = (int*)carve((size_t)(N + 1) * 4);
  int* cursor = (int*)carve((size_t)N * 4);
  const int nch = (N + 1023) / 1024;
  int* csum = (int*)carve((size_t)nch * 4);
  int* csr = (int*)carve((size_t)E * 4);

  hipMemsetAsync(cs, 0, (size_t)2 * N * 4, stream);

  k_prep<<<193, 256, 0, stream>>>(W0, W1, W2, b0, b1, b2, g0, be0, m0, v0, g1, be1, m1, v1,
                                  Wt, CA, CB);
  k_count<<<(E + 255) / 256, 256, 0, stream>>>(esrc, edst, cs, cd, E);
  k_norms<<<(N + 255) / 256, 256, 0, stream>>>(cs, cd, ns, nd, N);
  k_scan_partial<<<nch, 256, 0, stream>>>(cd, csum, N);
  k_scan_serial<<<1, 1, 0, stream>>>(csum, nch, rofs, N);
  k_scan_final<<<nch, 256, 0, stream>>>(cd, csum, rofs, cursor, N);
  k_fill<<<(E + 255) / 256, 256, 0, stream>>>(esrc, edst, cursor, csr, E);
  k_x16<<<(N * 32 + 255) / 256, 256, 0, stream>>>(x, ns, bufA, N);

  const int gb = (N + 127) / 128;
  const int sb = (N + 3) / 4;
  // layer 0
  k_gemm16<<<gb, 256, 0, stream>>>((const ushort*)bufA, Wt, (ushort*)hs16, N);
  k_spmm16<<<sb, 256, 0, stream>>>(hs16, csr, rofs, nd, ns, CA, CB, nullptr, bufA, N, 0);
  // layer 1
  k_gemm16<<<gb, 256, 0, stream>>>((const ushort*)bufA, Wt + 16384, (ushort*)hs16, N);
  k_spmm16<<<sb, 256, 0, stream>>>(hs16, csr, rofs, nd, ns, CA + D, CB + D, nullptr, bufA, N, 0);
  // layer 2
  k_gemm16<<<gb, 256, 0, stream>>>((const ushort*)bufA, Wt + 32768, (ushort*)hs16, N);
  k_spmm16<<<sb, 256, 0, stream>>>(hs16, csr, rofs, nd, ns, CA + 2 * D, CB + 2 * D,
                                   (float*)d_out, nullptr, N, 1);
}

// Round 3
// 404.282 us; speedup vs baseline: 1.4958x; 1.1145x over previous
//
#include <hip/hip_runtime.h>
#include <hip/hip_fp16.h>
#include <math.h>

#define D 128
#define NXCD 8

typedef _Float16 half8 __attribute__((ext_vector_type(8)));
typedef float f32x4 __attribute__((ext_vector_type(4)));

__device__ inline uint pack_f16x2(float a, float b) {
  __half2 h = __floats2half2_rn(a, b);
  return *reinterpret_cast<uint*>(&h);
}
__device__ inline float2 unpack_f16x2(uint p) {
  __half2 h = *reinterpret_cast<__half2*>(&p);
  return __half22float2(h);
}

// ---------------- count with XCD-local (L2) atomics + position record ----------------

__global__ void k_count2(const int* __restrict__ src, const int* __restrict__ dst,
                         int* __restrict__ cnts, int* __restrict__ cntd,
                         ushort* __restrict__ posrec, int E, int N) {
  int i = blockIdx.x * blockDim.x + threadIdx.x;
  if (i >= E) return;
  uint xcc;
  asm volatile("s_getreg_b32 %0, hwreg(HW_REG_XCC_ID)" : "=s"(xcc));
  xcc &= (NXCD - 1);
  const int s = src[i], d = dst[i];
  // L2-local RMW (no device-scope write-through); per-XCD private copies keep it correct
  int p = __hip_atomic_fetch_add(&cntd[xcc * N + d], 1, __ATOMIC_RELAXED,
                                 __HIP_MEMORY_SCOPE_WORKGROUP);
  __hip_atomic_fetch_add(&cnts[xcc * N + s], 1, __ATOMIC_RELAXED,
                         __HIP_MEMORY_SCOPE_WORKGROUP);
  posrec[i] = (ushort)((xcc << 12) | (p & 0xfff));
}

// ---------------- scans: rofs over summed in-degree, per-XCD bases, norms ----------------

__global__ __launch_bounds__(256) void k_scan_partial(const int* __restrict__ cntd,
                                                      int* __restrict__ csum, int n, int N) {
  __shared__ int sd[256];
  const int b = blockIdx.x, t = threadIdx.x;
  const int base = b * 1024 + t * 4;
  int s = 0;
#pragma unroll
  for (int i = 0; i < 4; ++i) {
    const int idx = base + i;
    if (idx < n) {
      int tot = 0;
#pragma unroll
      for (int x = 0; x < NXCD; ++x) tot += cntd[x * N + idx];
      s += tot;
    }
  }
  sd[t] = s; __syncthreads();
  for (int off = 128; off > 0; off >>= 1) {
    if (t < off) sd[t] += sd[t + off];
    __syncthreads();
  }
  if (t == 0) csum[b] = sd[0];
}

__global__ void k_scan_serial(int* __restrict__ csum, int nch,
                              int* __restrict__ rofs, int n) {
  if (blockIdx.x == 0 && threadIdx.x == 0) {
    int run = 0;
    for (int b = 0; b < nch; ++b) { int v = csum[b]; csum[b] = run; run += v; }
    rofs[n] = run;
  }
}

// cntd: in = per-XCD counts, out = per-XCD base offsets (in-place). Also ns/nd.
__global__ __launch_bounds__(256) void k_scan_final(const int* __restrict__ cnts,
                                                    int* __restrict__ cntd,
                                                    const int* __restrict__ csum,
                                                    int* __restrict__ rofs,
                                                    float* __restrict__ ns,
                                                    float* __restrict__ nd, int n, int N) {
  __shared__ int sd[256];
  const int b = blockIdx.x, t = threadIdx.x;
  const int base = b * 1024 + t * 4;
  int c8[4][NXCD];
  int v[4]; int s = 0;
#pragma unroll
  for (int i = 0; i < 4; ++i) {
    const int idx = base + i;
    int tot = 0;
    if (idx < n) {
#pragma unroll
      for (int x = 0; x < NXCD; ++x) { c8[i][x] = cntd[x * N + idx]; tot += c8[i][x]; }
    }
    v[i] = tot; s += tot;
  }
  sd[t] = s; __syncthreads();
  for (int off = 1; off < 256; off <<= 1) {
    int x = (t >= off) ? sd[t - off] : 0;
    __syncthreads();
    sd[t] += x;
    __syncthreads();
  }
  int o = sd[t] - s + csum[b];
#pragma unroll
  for (int i = 0; i < 4; ++i) {
    const int idx = base + i;
    if (idx < n) {
      rofs[idx] = o;
      int run = o;
#pragma unroll
      for (int x = 0; x < NXCD; ++x) { cntd[x * N + idx] = run; run += c8[i][x]; }
      int di = v[i]; if (di < 1) di = 1;
      nd[idx] = rsqrtf((float)di);
      int so = 0;
#pragma unroll
      for (int x = 0; x < NXCD; ++x) so += cnts[x * N + idx];
      if (so < 1) so = 1;
      ns[idx] = rsqrtf((float)so);
      o += v[i];
    }
  }
}

// ---------------- atomic-free scatter ----------------

__global__ void k_scatter(const int* __restrict__ src, const int* __restrict__ dst,
                          const ushort* __restrict__ posrec,
                          const int* __restrict__ xcdbase, int* __restrict__ csr,
                          int E, int N) {
  int i = blockIdx.x * blockDim.x + threadIdx.x;
  if (i < E) {
    const ushort pr = posrec[i];
    const int x = pr >> 12, p = pr & 0xfff;
    csr[xcdbase[x * N + dst[i]] + p] = src[i];
  }
}

// ---------------- prep: Wt[l][n][k] = f16(W_l[k][n]); CA/CB fold bias+BN ----------------

__global__ void k_prep(const float* __restrict__ W0, const float* __restrict__ W1,
                       const float* __restrict__ W2,
                       const float* __restrict__ b0, const float* __restrict__ b1,
                       const float* __restrict__ b2,
                       const float* __restrict__ g0, const float* __restrict__ be0,
                       const float* __restrict__ mu0, const float* __restrict__ vr0,
                       const float* __restrict__ g1, const float* __restrict__ be1,
                       const float* __restrict__ mu1, const float* __restrict__ vr1,
                       ushort* __restrict__ Wt, float* __restrict__ CA,
                       float* __restrict__ CB) {
  int b = blockIdx.x;
  if (b < 192) {
    int li = b * 256 + threadIdx.x;
    int l = li >> 14;
    int i = li & 16383;
    int n = i >> 7, k = i & 127;
    const float* W = (l == 0) ? W0 : ((l == 1) ? W1 : W2);
    Wt[li] = __half_as_ushort(__float2half_rn(W[k * D + n]));
  } else if (threadIdx.x < D) {
    int c = threadIdx.x;
    float A0 = g0[c] * rsqrtf(vr0[c] + 1e-5f);
    CA[c] = A0;
    CB[c] = (b0[c] - mu0[c]) * A0 + be0[c];
    float A1 = g1[c] * rsqrtf(vr1[c] + 1e-5f);
    CA[D + c] = A1;
    CB[D + c] = (b1[c] - mu1[c]) * A1 + be1[c];
    CA[2 * D + c] = 1.f;
    CB[2 * D + c] = b2[c];
  }
}

// ---------------- x16 = f16(x * ns) ----------------

__global__ void k_x16(const float* __restrict__ x, const float* __restrict__ ns,
                      uint* __restrict__ x16, int N) {
  int i = blockIdx.x * blockDim.x + threadIdx.x;
  if (i < N * 32) {
    int r = i >> 5;
    float4 v = reinterpret_cast<const float4*>(x)[i];
    float s = ns[r];
    uint2 u;
    u.x = pack_f16x2(v.x * s, v.y * s);
    u.y = pack_f16x2(v.z * s, v.w * s);
    reinterpret_cast<uint2*>(x16)[i] = u;
  }
}

// ---------------- MFMA GEMM (f16 in, f16 out) ----------------

__global__ __launch_bounds__(256) void k_gemm16(const ushort* __restrict__ A,
                                                const ushort* __restrict__ Wt,
                                                ushort* __restrict__ out, int M) {
  const int lane = threadIdx.x & 63;
  const int wv = threadIdx.x >> 6;
  const int m0 = (blockIdx.x * 4 + wv) * 32;
  if (m0 >= M) return;
  const int lr = lane & 15;
  const int kg = (lane >> 4) * 8;

  half8 hf[2][4];
  const half8 hz = {};
#pragma unroll
  for (int mt = 0; mt < 2; ++mt) {
    const int row = m0 + mt * 16 + lr;
    const bool ok = row < M;
#pragma unroll
    for (int kt = 0; kt < 4; ++kt)
      hf[mt][kt] = ok ? *reinterpret_cast<const half8*>(A + (size_t)row * D + kt * 32 + kg)
                      : hz;
  }

  f32x4 acc[8][2];
#pragma unroll
  for (int nt = 0; nt < 8; ++nt) {
    acc[nt][0] = (f32x4)(0.f);
    acc[nt][1] = (f32x4)(0.f);
  }

#pragma unroll
  for (int nt = 0; nt < 8; ++nt) {
    const ushort* wb = Wt + (size_t)(nt * 16 + lr) * D + kg;
#pragma unroll
    for (int kt = 0; kt < 4; ++kt) {
      half8 wf = *reinterpret_cast<const half8*>(wb + kt * 32);
      acc[nt][0] = __builtin_amdgcn_mfma_f32_16x16x32_f16(wf, hf[0][kt], acc[nt][0], 0, 0, 0);
      acc[nt][1] = __builtin_amdgcn_mfma_f32_16x16x32_f16(wf, hf[1][kt], acc[nt][1], 0, 0, 0);
    }
  }

  const int mo = lane & 15;
  const int no = (lane >> 4) * 4;
#pragma unroll
  for (int mt = 0; mt < 2; ++mt) {
    const int row = m0 + mt * 16 + mo;
    if (row < M) {
#pragma unroll
      for (int nt = 0; nt < 8; ++nt) {
        uint2 u;
        u.x = pack_f16x2(acc[nt][mt][0], acc[nt][mt][1]);
        u.y = pack_f16x2(acc[nt][mt][2], acc[nt][mt][3]);
        *reinterpret_cast<uint2*>(out + (size_t)row * D + nt * 16 + no) = u;
      }
    }
  }
}

// ---------------- SpMM: wave per dst row, 16 lanes x 16B per edge, 4 edge slots ----------------

__global__ __launch_bounds__(256) void k_spmm16(const uint* __restrict__ hs,
                                                const int* __restrict__ csr,
                                                const int* __restrict__ rofs,
                                                const float* __restrict__ nd,
                                                const float* __restrict__ ns,
                                                const float* __restrict__ CA,
                                                const float* __restrict__ CB,
                                                float* __restrict__ outf,
                                                uint* __restrict__ hnext,
                                                int N, int last) {
  const int t = threadIdx.x;
  const int lane = t & 63;
  const int d = blockIdx.x * 4 + (t >> 6);
  if (d >= N) return;
  const int sub = lane >> 4;   // edge slot 0..3
  const int c16 = lane & 15;   // 8-col group
  const int beg = rofs[d], end = rofs[d + 1];

  float acc[8];
#pragma unroll
  for (int j = 0; j < 8; ++j) acc[j] = 0.f;

  for (int e = beg + sub; e < end; e += 4) {
    const int s = csr[e];
    const uint4 v = *reinterpret_cast<const uint4*>(hs + (size_t)s * 64 + c16 * 4);
    const float2 a0 = unpack_f16x2(v.x);
    const float2 a1 = unpack_f16x2(v.y);
    const float2 a2 = unpack_f16x2(v.z);
    const float2 a3 = unpack_f16x2(v.w);
    acc[0] += a0.x; acc[1] += a0.y;
    acc[2] += a1.x; acc[3] += a1.y;
    acc[4] += a2.x; acc[5] += a2.y;
    acc[6] += a3.x; acc[7] += a3.y;
  }
#pragma unroll
  for (int j = 0; j < 8; ++j) {
    acc[j] += __shfl_xor(acc[j], 16);
    acc[j] += __shfl_xor(acc[j], 32);
  }
  if (sub == 0) {
    const float ndv = nd[d];
    const float4 ca0 = *reinterpret_cast<const float4*>(CA + c16 * 8);
    const float4 ca1 = *reinterpret_cast<const float4*>(CA + c16 * 8 + 4);
    const float4 cb0 = *reinterpret_cast<const float4*>(CB + c16 * 8);
    const float4 cb1 = *reinterpret_cast<const float4*>(CB + c16 * 8 + 4);
    float r[8];
    r[0] = acc[0] * ndv * ca0.x + cb0.x;
    r[1] = acc[1] * ndv * ca0.y + cb0.y;
    r[2] = acc[2] * ndv * ca0.z + cb0.z;
    r[3] = acc[3] * ndv * ca0.w + cb0.w;
    r[4] = acc[4] * ndv * ca1.x + cb1.x;
    r[5] = acc[5] * ndv * ca1.y + cb1.y;
    r[6] = acc[6] * ndv * ca1.z + cb1.z;
    r[7] = acc[7] * ndv * ca1.w + cb1.w;
    if (!last) {
      const float s = ns[d];
#pragma unroll
      for (int j = 0; j < 8; ++j) r[j] = fmaxf(r[j], 0.f) * s;
      uint4 u;
      u.x = pack_f16x2(r[0], r[1]);
      u.y = pack_f16x2(r[2], r[3]);
      u.z = pack_f16x2(r[4], r[5]);
      u.w = pack_f16x2(r[6], r[7]);
      *reinterpret_cast<uint4*>(hnext + (size_t)d * 64 + c16 * 4) = u;
    } else {
      float4 o0 = make_float4(r[0], r[1], r[2], r[3]);
      float4 o1 = make_float4(r[4], r[5], r[6], r[7]);
      *reinterpret_cast<float4*>(outf + (size_t)d * D + c16 * 8) = o0;
      *reinterpret_cast<float4*>(outf + (size_t)d * D + c16 * 8 + 4) = o1;
    }
  }
}

// ---------------- launch ----------------

extern "C" void kernel_launch(void* const* d_in, const int* in_sizes, int n_in,
                              void* d_out, int out_size, void* d_ws, size_t ws_size,
                              hipStream_t stream) {
  const float* x = (const float*)d_in[0];
  const int* esrc = (const int*)d_in[1];
  const int* edst = (const int*)d_in[2];
  const float* W0 = (const float*)d_in[3];
  const float* b0 = (const float*)d_in[4];
  const float* W1 = (const float*)d_in[5];
  const float* b1 = (const float*)d_in[6];
  const float* W2 = (const float*)d_in[7];
  const float* b2 = (const float*)d_in[8];
  const float* g0 = (const float*)d_in[9];
  const float* be0 = (const float*)d_in[10];
  const float* m0 = (const float*)d_in[11];
  const float* v0 = (const float*)d_in[12];
  const float* g1 = (const float*)d_in[13];
  const float* be1 = (const float*)d_in[14];
  const float* m1 = (const float*)d_in[15];
  const float* v1 = (const float*)d_in[16];
  const int N = in_sizes[0] / D;
  const int E = in_sizes[1];

  char* p = (char*)d_ws;
  auto carve = [&](size_t bytes) {
    char* r = p;
    p += (bytes + 255) & ~(size_t)255;
    return (void*)r;
  };
  uint* hs16 = (uint*)carve((size_t)N * 64 * 4);       // GEMM out / SpMM in (f16 packed)
  ushort* Wt = (ushort*)carve((size_t)3 * D * D * 2);
  float* CA = (float*)carve((size_t)3 * D * 4);
  float* CB = (float*)carve((size_t)3 * D * 4);
  float* ns = (float*)carve((size_t)N * 4);
  float* nd = (float*)carve((size_t)N * 4);
  int* cnts = (int*)carve((size_t)2 * NXCD * N * 4);   // cnts | cntd contiguous -> one memset
  int* cntd = cnts + (size_t)NXCD * N;                 // becomes xcdbase in-place
  int* rofs = (int*)carve((size_t)(N + 1) * 4);
  const int nch = (N + 1023) / 1024;
  int* csum = (int*)carve((size_t)nch * 4);
  ushort* posrec = (ushort*)carve((size_t)E * 2);
  int* csr = (int*)carve((size_t)E * 4);
  uint* bufA = (uint*)d_out;  // GEMM input ping buffer lives in d_out (fully rewritten)

  hipMemsetAsync(cnts, 0, (size_t)2 * NXCD * N * 4, stream);

  k_prep<<<193, 256, 0, stream>>>(W0, W1, W2, b0, b1, b2, g0, be0, m0, v0, g1, be1, m1, v1,
                                  Wt, CA, CB);
  k_count2<<<(E + 255) / 256, 256, 0, stream>>>(esrc, edst, cnts, cntd, posrec, E, N);
  k_scan_partial<<<nch, 256, 0, stream>>>(cntd, csum, N, N);
  k_scan_serial<<<1, 1, 0, stream>>>(csum, nch, rofs, N);
  k_scan_final<<<nch, 256, 0, stream>>>(cnts, cntd, csum, rofs, ns, nd, N, N);
  k_scatter<<<(E + 255) / 256, 256, 0, stream>>>(esrc, edst, posrec, cntd, csr, E, N);
  k_x16<<<(N * 32 + 255) / 256, 256, 0, stream>>>(x, ns, bufA, N);

  const int gb = (N + 127) / 128;
  const int sb = (N + 3) / 4;
  // layer 0
  k_gemm16<<<gb, 256, 0, stream>>>((const ushort*)bufA, Wt, (ushort*)hs16, N);
  k_spmm16<<<sb, 256, 0, stream>>>(hs16, csr, rofs, nd, ns, CA, CB, nullptr, bufA, N, 0);
  // layer 1
  k_gemm16<<<gb, 256, 0, stream>>>((const ushort*)bufA, Wt + 16384, (ushort*)hs16, N);
  k_spmm16<<<sb, 256, 0, stream>>>(hs16, csr, rofs, nd, ns, CA + D, CB + D, nullptr, bufA, N, 0);
  // layer 2
  k_gemm16<<<gb, 256, 0, stream>>>((const ushort*)bufA, Wt + 32768, (ushort*)hs16, N);
  k_spmm16<<<sb, 256, 0, stream>>>(hs16, csr, rofs, nd, ns, CA + 2 * D, CB + 2 * D,
                                   (float*)d_out, nullptr, N, 1);
}

// Round 4
// 340.665 us; speedup vs baseline: 1.7751x; 1.1867x over previous
//
#include <hip/hip_runtime.h>
#include <hip/hip_fp16.h>
#include <math.h>

#define D 128
#define NCH 8          // node chunks
#define NSL 32         // edge slices
#define PBINS 6272     // packed uint counters per chunk (covers 12544 bins >= ceil(100000/8))

typedef _Float16 half8 __attribute__((ext_vector_type(8)));
typedef float f32x4 __attribute__((ext_vector_type(4)));

__device__ inline uint pack_f16x2(float a, float b) {
  __half2 h = __floats2half2_rn(a, b);
  return *reinterpret_cast<uint*>(&h);
}
__device__ inline float2 unpack_f16x2(uint p) {
  __half2 h = *reinterpret_cast<__half2*>(&p);
  return __half22float2(h);
}

// ---------------- histogram: chunked LDS, packed u16 counters, rank recording ----------------

__global__ __launch_bounds__(256) void k_hist(const int* __restrict__ esrc,
                                              const int* __restrict__ edst,
                                              uint* __restrict__ partial_d,
                                              uint* __restrict__ partial_s,
                                              ushort* __restrict__ rank16,
                                              int E, int N, int BPC, int S) {
  __shared__ uint hd[PBINS];
  __shared__ uint hsrc[PBINS];
  const int t = threadIdx.x;
  const int c = blockIdx.x / NSL;
  const int b = blockIdx.x % NSL;
  for (int j = t; j < PBINS; j += 256) { hd[j] = 0u; hsrc[j] = 0u; }
  __syncthreads();
  const int c0 = c * BPC;
  const int c1 = min(c0 + BPC, N);
  const int i0 = b * S;            // S is a multiple of 4 -> 4-aligned slice starts
  const int i1 = min(i0 + S, E);
  for (int vi = (i0 >> 2) + t; vi < ((i1 + 3) >> 2); vi += 256) {
    const int ib = vi << 2;
    int dv[4], sv[4];
    if (ib + 3 < i1) {
      const int4 d4 = reinterpret_cast<const int4*>(edst)[vi];
      const int4 s4 = reinterpret_cast<const int4*>(esrc)[vi];
      dv[0] = d4.x; dv[1] = d4.y; dv[2] = d4.z; dv[3] = d4.w;
      sv[0] = s4.x; sv[1] = s4.y; sv[2] = s4.z; sv[3] = s4.w;
    } else {
#pragma unroll
      for (int k = 0; k < 4; ++k) {
        dv[k] = (ib + k < i1) ? edst[ib + k] : -1;
        sv[k] = (ib + k < i1) ? esrc[ib + k] : -1;
      }
    }
#pragma unroll
    for (int k = 0; k < 4; ++k) {
      const int d = dv[k];
      if (d >= c0 && d < c1) {
        const uint bl = (uint)(d - c0);
        const uint sh = (bl & 1u) * 16u;
        const uint old = atomicAdd(&hd[bl >> 1], 1u << sh);
        rank16[ib + k] = (ushort)((old >> sh) & 0xffffu);
      }
      const int s = sv[k];
      if (s >= c0 && s < c1) {
        const uint bl = (uint)(s - c0);
        atomicAdd(&hsrc[bl >> 1], 1u << (16u * (bl & 1u)));
      }
    }
  }
  __syncthreads();
  uint* pd = partial_d + (size_t)blockIdx.x * PBINS;
  uint* ps = partial_s + (size_t)blockIdx.x * PBINS;
  for (int j = t; j < PBINS; j += 256) { pd[j] = hd[j]; ps[j] = hsrc[j]; }
}

// ---------------- reduce: totals, norms, exclusive prefix over slices (in place) ----------------

__global__ __launch_bounds__(256) void k_reduce(uint* __restrict__ partial_d,
                                                const uint* __restrict__ partial_s,
                                                int* __restrict__ totd,
                                                float* __restrict__ ns,
                                                float* __restrict__ nd, int N, int BPC) {
  const int j = blockIdx.x * 256 + threadIdx.x;  // packed-pair index (BPC is even)
  const int bin0 = j * 2;
  if (bin0 >= N) return;
  const int c = bin0 / BPC;
  const int jj = (bin0 - c * BPC) >> 1;
  uint* pd = partial_d + (size_t)c * NSL * PBINS + jj;
  const uint* ps = partial_s + (size_t)c * NSL * PBINS + jj;
  uint p0 = 0, p1 = 0, s0 = 0, s1 = 0;
#pragma unroll
  for (int b = 0; b < NSL; ++b) {
    const uint v = pd[(size_t)b * PBINS];
    pd[(size_t)b * PBINS] = p0 | (p1 << 16);
    p0 += v & 0xffffu; p1 += v >> 16;
    const uint w = ps[(size_t)b * PBINS];
    s0 += w & 0xffffu; s1 += w >> 16;
  }
  totd[bin0] = (int)p0;
  nd[bin0] = rsqrtf((float)max(p0, 1u));
  ns[bin0] = rsqrtf((float)max(s0, 1u));
  if (bin0 + 1 < N) {
    totd[bin0 + 1] = (int)p1;
    nd[bin0 + 1] = rsqrtf((float)max(p1, 1u));
    ns[bin0 + 1] = rsqrtf((float)max(s1, 1u));
  }
}

// ---------------- rofs scan over totd ----------------

__global__ __launch_bounds__(256) void k_scan_partial(const int* __restrict__ totd,
                                                      int* __restrict__ csum, int n) {
  __shared__ int sd[256];
  const int b = blockIdx.x, t = threadIdx.x;
  const int base = b * 1024 + t * 4;
  int s = 0;
#pragma unroll
  for (int i = 0; i < 4; ++i) { int idx = base + i; if (idx < n) s += totd[idx]; }
  sd[t] = s; __syncthreads();
  for (int off = 128; off > 0; off >>= 1) {
    if (t < off) sd[t] += sd[t + off];
    __syncthreads();
  }
  if (t == 0) csum[b] = sd[0];
}

__global__ void k_scan_serial(int* __restrict__ csum, int nch,
                              int* __restrict__ rofs, int n) {
  if (blockIdx.x == 0 && threadIdx.x == 0) {
    int run = 0;
    for (int b = 0; b < nch; ++b) { int v = csum[b]; csum[b] = run; run += v; }
    rofs[n] = run;
  }
}

__global__ __launch_bounds__(256) void k_scan_final(const int* __restrict__ totd,
                                                    const int* __restrict__ csum,
                                                    int* __restrict__ rofs, int n) {
  __shared__ int sd[256];
  const int b = blockIdx.x, t = threadIdx.x;
  const int base = b * 1024 + t * 4;
  int v[4]; int s = 0;
#pragma unroll
  for (int i = 0; i < 4; ++i) { v[i] = (base + i < n) ? totd[base + i] : 0; s += v[i]; }
  sd[t] = s; __syncthreads();
  for (int off = 1; off < 256; off <<= 1) {
    int x = (t >= off) ? sd[t - off] : 0;
    __syncthreads();
    sd[t] += x;
    __syncthreads();
  }
  int o = sd[t] - s + csum[b];
#pragma unroll
  for (int i = 0; i < 4; ++i) {
    if (base + i < n) { rofs[base + i] = o; o += v[i]; }
  }
}

// ---------------- atomic-free scatter ----------------

__global__ void k_scatter2(const int* __restrict__ esrc, const int* __restrict__ edst,
                           const ushort* __restrict__ rank16,
                           const uint* __restrict__ partial_d,
                           const int* __restrict__ rofs, int* __restrict__ csr,
                           int E, int BPC, int S) {
  const int i = blockIdx.x * 256 + threadIdx.x;
  if (i >= E) return;
  const int d = edst[i];
  const int c = d / BPC;
  const uint bl = (uint)(d - c * BPC);
  const int b = i / S;
  const uint pr = partial_d[(size_t)(c * NSL + b) * PBINS + (bl >> 1)];
  const uint p = (bl & 1u) ? (pr >> 16) : (pr & 0xffffu);
  csr[rofs[d] + (int)p + (int)rank16[i]] = esrc[i];
}

// ---------------- prep: Wt[l][n][k] = f16(W_l[k][n]); CA/CB fold bias+BN ----------------

__global__ void k_prep(const float* __restrict__ W0, const float* __restrict__ W1,
                       const float* __restrict__ W2,
                       const float* __restrict__ b0, const float* __restrict__ b1,
                       const float* __restrict__ b2,
                       const float* __restrict__ g0, const float* __restrict__ be0,
                       const float* __restrict__ mu0, const float* __restrict__ vr0,
                       const float* __restrict__ g1, const float* __restrict__ be1,
                       const float* __restrict__ mu1, const float* __restrict__ vr1,
                       ushort* __restrict__ Wt, float* __restrict__ CA,
                       float* __restrict__ CB) {
  int b = blockIdx.x;
  if (b < 192) {
    int li = b * 256 + threadIdx.x;
    int l = li >> 14;
    int i = li & 16383;
    int n = i >> 7, k = i & 127;
    const float* W = (l == 0) ? W0 : ((l == 1) ? W1 : W2);
    Wt[li] = __half_as_ushort(__float2half_rn(W[k * D + n]));
  } else if (threadIdx.x < D) {
    int c = threadIdx.x;
    float A0 = g0[c] * rsqrtf(vr0[c] + 1e-5f);
    CA[c] = A0;
    CB[c] = (b0[c] - mu0[c]) * A0 + be0[c];
    float A1 = g1[c] * rsqrtf(vr1[c] + 1e-5f);
    CA[D + c] = A1;
    CB[D + c] = (b1[c] - mu1[c]) * A1 + be1[c];
    CA[2 * D + c] = 1.f;
    CB[2 * D + c] = b2[c];
  }
}

// ---------------- x16 = f16(x * ns) ----------------

__global__ void k_x16(const float* __restrict__ x, const float* __restrict__ ns,
                      uint* __restrict__ x16, int N) {
  int i = blockIdx.x * blockDim.x + threadIdx.x;
  if (i < N * 32) {
    int r = i >> 5;
    float4 v = reinterpret_cast<const float4*>(x)[i];
    float s = ns[r];
    uint2 u;
    u.x = pack_f16x2(v.x * s, v.y * s);
    u.y = pack_f16x2(v.z * s, v.w * s);
    reinterpret_cast<uint2*>(x16)[i] = u;
  }
}

// ---------------- MFMA GEMM (f16 in, f16 out) ----------------

__global__ __launch_bounds__(256) void k_gemm16(const ushort* __restrict__ A,
                                                const ushort* __restrict__ Wt,
                                                ushort* __restrict__ out, int M) {
  const int lane = threadIdx.x & 63;
  const int wv = threadIdx.x >> 6;
  const int m0 = (blockIdx.x * 4 + wv) * 32;
  if (m0 >= M) return;
  const int lr = lane & 15;
  const int kg = (lane >> 4) * 8;

  half8 hf[2][4];
  const half8 hz = {};
#pragma unroll
  for (int mt = 0; mt < 2; ++mt) {
    const int row = m0 + mt * 16 + lr;
    const bool ok = row < M;
#pragma unroll
    for (int kt = 0; kt < 4; ++kt)
      hf[mt][kt] = ok ? *reinterpret_cast<const half8*>(A + (size_t)row * D + kt * 32 + kg)
                      : hz;
  }

  f32x4 acc[8][2];
#pragma unroll
  for (int nt = 0; nt < 8; ++nt) {
    acc[nt][0] = (f32x4)(0.f);
    acc[nt][1] = (f32x4)(0.f);
  }

#pragma unroll
  for (int nt = 0; nt < 8; ++nt) {
    const ushort* wb = Wt + (size_t)(nt * 16 + lr) * D + kg;
#pragma unroll
    for (int kt = 0; kt < 4; ++kt) {
      half8 wf = *reinterpret_cast<const half8*>(wb + kt * 32);
      acc[nt][0] = __builtin_amdgcn_mfma_f32_16x16x32_f16(wf, hf[0][kt], acc[nt][0], 0, 0, 0);
      acc[nt][1] = __builtin_amdgcn_mfma_f32_16x16x32_f16(wf, hf[1][kt], acc[nt][1], 0, 0, 0);
    }
  }

  const int mo = lane & 15;
  const int no = (lane >> 4) * 4;
#pragma unroll
  for (int mt = 0; mt < 2; ++mt) {
    const int row = m0 + mt * 16 + mo;
    if (row < M) {
#pragma unroll
      for (int nt = 0; nt < 8; ++nt) {
        uint2 u;
        u.x = pack_f16x2(acc[nt][mt][0], acc[nt][mt][1]);
        u.y = pack_f16x2(acc[nt][mt][2], acc[nt][mt][3]);
        *reinterpret_cast<uint2*>(out + (size_t)row * D + nt * 16 + no) = u;
      }
    }
  }
}

// ---------------- SpMM: wave per dst row, 16 lanes x 16B per edge, 4 edge slots ----------------

__global__ __launch_bounds__(256) void k_spmm16(const uint* __restrict__ hs,
                                                const int* __restrict__ csr,
                                                const int* __restrict__ rofs,
                                                const float* __restrict__ nd,
                                                const float* __restrict__ ns,
                                                const float* __restrict__ CA,
                                                const float* __restrict__ CB,
                                                float* __restrict__ outf,
                                                uint* __restrict__ hnext,
                                                int N, int last) {
  const int t = threadIdx.x;
  const int lane = t & 63;
  const int d = blockIdx.x * 4 + (t >> 6);
  if (d >= N) return;
  const int sub = lane >> 4;   // edge slot 0..3
  const int c16 = lane & 15;   // 8-col group
  const int beg = rofs[d], end = rofs[d + 1];

  float acc[8];
#pragma unroll
  for (int j = 0; j < 8; ++j) acc[j] = 0.f;

  for (int e = beg + sub; e < end; e += 4) {
    const int s = csr[e];
    const uint4 v = *reinterpret_cast<const uint4*>(hs + (size_t)s * 64 + c16 * 4);
    const float2 a0 = unpack_f16x2(v.x);
    const float2 a1 = unpack_f16x2(v.y);
    const float2 a2 = unpack_f16x2(v.z);
    const float2 a3 = unpack_f16x2(v.w);
    acc[0] += a0.x; acc[1] += a0.y;
    acc[2] += a1.x; acc[3] += a1.y;
    acc[4] += a2.x; acc[5] += a2.y;
    acc[6] += a3.x; acc[7] += a3.y;
  }
#pragma unroll
  for (int j = 0; j < 8; ++j) {
    acc[j] += __shfl_xor(acc[j], 16);
    acc[j] += __shfl_xor(acc[j], 32);
  }
  if (sub == 0) {
    const float ndv = nd[d];
    const float4 ca0 = *reinterpret_cast<const float4*>(CA + c16 * 8);
    const float4 ca1 = *reinterpret_cast<const float4*>(CA + c16 * 8 + 4);
    const float4 cb0 = *reinterpret_cast<const float4*>(CB + c16 * 8);
    const float4 cb1 = *reinterpret_cast<const float4*>(CB + c16 * 8 + 4);
    float r[8];
    r[0] = acc[0] * ndv * ca0.x + cb0.x;
    r[1] = acc[1] * ndv * ca0.y + cb0.y;
    r[2] = acc[2] * ndv * ca0.z + cb0.z;
    r[3] = acc[3] * ndv * ca0.w + cb0.w;
    r[4] = acc[4] * ndv * ca1.x + cb1.x;
    r[5] = acc[5] * ndv * ca1.y + cb1.y;
    r[6] = acc[6] * ndv * ca1.z + cb1.z;
    r[7] = acc[7] * ndv * ca1.w + cb1.w;
    if (!last) {
      const float s = ns[d];
#pragma unroll
      for (int j = 0; j < 8; ++j) r[j] = fmaxf(r[j], 0.f) * s;
      uint4 u;
      u.x = pack_f16x2(r[0], r[1]);
      u.y = pack_f16x2(r[2], r[3]);
      u.z = pack_f16x2(r[4], r[5]);
      u.w = pack_f16x2(r[6], r[7]);
      *reinterpret_cast<uint4*>(hnext + (size_t)d * 64 + c16 * 4) = u;
    } else {
      float4 o0 = make_float4(r[0], r[1], r[2], r[3]);
      float4 o1 = make_float4(r[4], r[5], r[6], r[7]);
      *reinterpret_cast<float4*>(outf + (size_t)d * D + c16 * 8) = o0;
      *reinterpret_cast<float4*>(outf + (size_t)d * D + c16 * 8 + 4) = o1;
    }
  }
}

// ---------------- launch ----------------

extern "C" void kernel_launch(void* const* d_in, const int* in_sizes, int n_in,
                              void* d_out, int out_size, void* d_ws, size_t ws_size,
                              hipStream_t stream) {
  const float* x = (const float*)d_in[0];
  const int* esrc = (const int*)d_in[1];
  const int* edst = (const int*)d_in[2];
  const float* W0 = (const float*)d_in[3];
  const float* b0 = (const float*)d_in[4];
  const float* W1 = (const float*)d_in[5];
  const float* b1 = (const float*)d_in[6];
  const float* W2 = (const float*)d_in[7];
  const float* b2 = (const float*)d_in[8];
  const float* g0 = (const float*)d_in[9];
  const float* be0 = (const float*)d_in[10];
  const float* m0 = (const float*)d_in[11];
  const float* v0 = (const float*)d_in[12];
  const float* g1 = (const float*)d_in[13];
  const float* be1 = (const float*)d_in[14];
  const float* m1 = (const float*)d_in[15];
  const float* v1 = (const float*)d_in[16];
  const int N = in_sizes[0] / D;
  const int E = in_sizes[1];

  const int BPC = (((N + NCH - 1) / NCH) + 1) & ~1;        // even bins/chunk (<= 12544)
  const int S = (((E + NSL - 1) / NSL) + 3) & ~3;          // 4-aligned slice size

  char* p = (char*)d_ws;
  auto carve = [&](size_t bytes) {
    char* r = p;
    p += (bytes + 255) & ~(size_t)255;
    return (void*)r;
  };
  uint* hs16 = (uint*)carve((size_t)N * 64 * 4);           // GEMM out / SpMM in (f16 packed)
  ushort* Wt = (ushort*)carve((size_t)3 * D * D * 2);
  float* CA = (float*)carve((size_t)3 * D * 4);
  float* CB = (float*)carve((size_t)3 * D * 4);
  float* ns = (float*)carve((size_t)N * 4);
  float* nd = (float*)carve((size_t)N * 4);
  uint* partial_d = (uint*)carve((size_t)NCH * NSL * PBINS * 4);
  uint* partial_s = (uint*)carve((size_t)NCH * NSL * PBINS * 4);
  ushort* rank16 = (ushort*)carve((size_t)E * 2);
  int* totd = (int*)carve((size_t)N * 4);
  int* rofs = (int*)carve((size_t)(N + 1) * 4);
  const int nch = (N + 1023) / 1024;
  int* csum = (int*)carve((size_t)nch * 4);
  int* csr = (int*)carve((size_t)E * 4);
  uint* bufA = (uint*)d_out;  // GEMM input ping buffer lives in d_out (fully rewritten)

  k_prep<<<193, 256, 0, stream>>>(W0, W1, W2, b0, b1, b2, g0, be0, m0, v0, g1, be1, m1, v1,
                                  Wt, CA, CB);
  k_hist<<<NCH * NSL, 256, 0, stream>>>(esrc, edst, partial_d, partial_s, rank16, E, N, BPC, S);
  k_reduce<<<((N + 1) / 2 + 255) / 256, 256, 0, stream>>>(partial_d, partial_s, totd, ns, nd,
                                                          N, BPC);
  k_scan_partial<<<nch, 256, 0, stream>>>(totd, csum, N);
  k_scan_serial<<<1, 1, 0, stream>>>(csum, nch, rofs, N);
  k_scan_final<<<nch, 256, 0, stream>>>(totd, csum, rofs, N);
  k_scatter2<<<(E + 255) / 256, 256, 0, stream>>>(esrc, edst, rank16, partial_d, rofs, csr,
                                                  E, BPC, S);
  k_x16<<<(N * 32 + 255) / 256, 256, 0, stream>>>(x, ns, bufA, N);

  const int gb = (N + 127) / 128;
  const int sb = (N + 3) / 4;
  // layer 0
  k_gemm16<<<gb, 256, 0, stream>>>((const ushort*)bufA, Wt, (ushort*)hs16, N);
  k_spmm16<<<sb, 256, 0, stream>>>(hs16, csr, rofs, nd, ns, CA, CB, nullptr, bufA, N, 0);
  // layer 1
  k_gemm16<<<gb, 256, 0, stream>>>((const ushort*)bufA, Wt + 16384, (ushort*)hs16, N);
  k_spmm16<<<sb, 256, 0, stream>>>(hs16, csr, rofs, nd, ns, CA + D, CB + D, nullptr, bufA, N, 0);
  // layer 2
  k_gemm16<<<gb, 256, 0, stream>>>((const ushort*)bufA, Wt + 32768, (ushort*)hs16, N);
  k_spmm16<<<sb, 256, 0, stream>>>(hs16, csr, rofs, nd, ns, CA + 2 * D, CB + 2 * D,
                                   (float*)d_out, nullptr, N, 1);
}